// Round 1
// baseline (16630.684 us; speedup 1.0000x reference)
//
#include <hip/hip_runtime.h>
#include <stdint.h>
#include <stddef.h>

// Persistent 2-layer LSTM decoder, B=1024, H=256, T=512.
// 16 groups x 16 WGs x 256 threads. WG owns 16 hidden units (both layers),
// weights register-resident as f16 MFMA B-fragments. 2 group barriers/step.

#define NGROUP 16
#define GWG    16
#define NTHR   256
#define TSTEPS 512

typedef _Float16 half8 __attribute__((ext_vector_type(8)));
typedef float    f32x4 __attribute__((ext_vector_type(4)));

#define OUT_ELEMS   33554432   // 1024*512*64
#define HF_ELEMS    524288     // 2*1024*256
#define HBUF_ELEMS  16384      // 64*256 (f16) per layer/parity
#define GROUP_WS_BYTES 131072  // 4 bufs * 16384 * 2B
#define WS_HBUF_OFF 4096
#define WS_NEEDED   (WS_HBUF_OFF + NGROUP * GROUP_WS_BYTES)

__device__ __forceinline__ float sigm(float x)   { return 1.0f / (1.0f + __expf(-x)); }
__device__ __forceinline__ float tanh_f(float x) { return 1.0f - 2.0f / (__expf(2.0f * x) + 1.0f); }

__device__ __forceinline__ void group_barrier(int* ctr, int* phase) {
  __syncthreads();
  if (threadIdx.x == 0) {
    __threadfence();                 // release: drain our writes to coherent point
    atomicAdd(ctr, 1);               // device-scope
    const int target = GWG * (++(*phase));
    while (__hip_atomic_load(ctr, __ATOMIC_RELAXED, __HIP_MEMORY_SCOPE_AGENT) < target)
      __builtin_amdgcn_s_sleep(1);
    __threadfence();                 // acquire: invalidate L1/L2 before group reads
  }
  __syncthreads();
}

__global__ __launch_bounds__(NTHR, 1)
void decoder_kernel(const float* __restrict__ h0in, const float* __restrict__ c0in,
                    const float* __restrict__ Wih0, const float* __restrict__ Whh0,
                    const float* __restrict__ bih0, const float* __restrict__ bhh0,
                    const float* __restrict__ Wih1, const float* __restrict__ Whh1,
                    const float* __restrict__ bih1, const float* __restrict__ bhh1,
                    const float* __restrict__ Wfc,  const float* __restrict__ bfc,
                    float* __restrict__ out, char* __restrict__ ws)
{
  const int tid  = threadIdx.x;
  const int lane = tid & 63;
  const int wave = tid >> 6;
  const int mi   = wave >> 1;   // M half (32 chains)
  const int ni   = wave & 1;    // N half: ni=0 -> {i,g}, ni=1 -> {f,o}
  const int q    = lane >> 4;   // quad
  const int u    = lane & 15;   // unit-in-slice / frag col / frag m

  // XCD-aware swizzle: blocks with same (b&7) share an XCD (round-robin dispatch)
  const int b = blockIdx.x;
  const int g = (b & 7) * 2 + ((b >> 3) >> 4);  // group 0..15
  const int w = (b >> 3) & 15;                  // member 0..15 (unit slice)

  int* ctr = (int*)(ws + (size_t)g * 128);
  _Float16* hb_base = (_Float16*)(ws + WS_HBUF_OFF + (size_t)g * GROUP_WS_BYTES);
  auto hbL = [&](int layer, int par) { return hb_base + (size_t)(layer * 2 + par) * HBUF_ELEMS; };

  __shared__ __align__(16) _Float16 xbuf[64 * 72];   // 72-elem stride (bank pad)
  __shared__ __align__(16) float    exch[2 * 8 * 64];
  __shared__ __align__(16) float    predbuf[64 * 68];

  // ---------------- weight fragments (register-resident, f16) ----------------
  // gates = act @ W^T : A[m=chain][k], B[k][n=gate-row].  B-frag: n=lane&15, k=q*8+j.
  half8 bL0[2][10]; half8 bL1[2][16]; half8 bFC[2][8];
  float biasL0[2], biasL1[2], biasFC[2];
  #pragma unroll
  for (int nt = 0; nt < 2; ++nt) {
    // gate-type base: ni=0 tiles {i(0), g(512)}, ni=1 tiles {f(256), o(768)}
    const int base0 = (ni == 0) ? (nt == 0 ? 0 : 512) : (nt == 0 ? 256 : 768);
    const int row = base0 + w * 16 + u;
    biasL0[nt] = bih0[row] + bhh0[row];
    biasL1[nt] = bih1[row] + bhh1[row];
    #pragma unroll
    for (int kt = 0; kt < 10; ++kt) {   // L0: K = 64(x) + 256(h0)
      const int k0 = kt * 32 + q * 8;
      const float* src = (kt < 2) ? (Wih0 + (size_t)row * 64 + k0)
                                  : (Whh0 + (size_t)row * 256 + (k0 - 64));
      half8 v;
      #pragma unroll
      for (int j = 0; j < 8; ++j) v[j] = (_Float16)src[j];
      bL0[nt][kt] = v;
    }
    #pragma unroll
    for (int kt = 0; kt < 16; ++kt) {   // L1: K = 256(h0new) + 256(h1)
      const int k0 = kt * 32 + q * 8;
      const float* src = (kt < 8) ? (Wih1 + (size_t)row * 256 + k0)
                                  : (Whh1 + (size_t)row * 256 + (k0 - 256));
      half8 v;
      #pragma unroll
      for (int j = 0; j < 8; ++j) v[j] = (_Float16)src[j];
      bL1[nt][kt] = v;
    }
    const int rowF = ni * 32 + nt * 16 + u;  // FC: no reorder
    biasFC[nt] = bfc[rowF];
    #pragma unroll
    for (int kt = 0; kt < 8; ++kt) {
      const float* src = Wfc + (size_t)rowF * 256 + kt * 32 + q * 8;
      half8 v;
      #pragma unroll
      for (int j = 0; j < 8; ++j) v[j] = (_Float16)src[j];
      bFC[nt][kt] = v;
    }
  }

  // ---------------- state init ----------------
  float c0st[2][4], c1st[2][4], h0sv[2][4], h1sv[2][4];
  #pragma unroll
  for (int mt = 0; mt < 2; ++mt)
    #pragma unroll
    for (int r = 0; r < 4; ++r) { c0st[mt][r] = 0; c1st[mt][r] = 0; h0sv[mt][r] = 0; h1sv[mt][r] = 0; }
  if (ni == 1) {  // ni=1 waves own c-state in D-frag layout: m = mi*32+mt*16+q*4+r, unit = w*16+u
    #pragma unroll
    for (int mt = 0; mt < 2; ++mt)
      #pragma unroll
      for (int r = 0; r < 4; ++r) {
        const int ch = g * 64 + mi * 32 + mt * 16 + q * 4 + r;
        c0st[mt][r] = c0in[(size_t)ch * 256 + w * 16 + u];
        c1st[mt][r] = c0in[262144 + (size_t)ch * 256 + w * 16 + u];
      }
  }
  {  // initial h -> parity-1 buffers (each WG writes its 16-unit column slice)
    const int chain = tid >> 2, u4 = (tid & 3) * 4;
    #pragma unroll
    for (int l = 0; l < 2; ++l) {
      const float* s = h0in + (size_t)l * 262144 + (size_t)(g * 64 + chain) * 256 + w * 16 + u4;
      _Float16* d = hbL(l, 1) + (size_t)chain * 256 + w * 16 + u4;
      #pragma unroll
      for (int j = 0; j < 4; ++j) d[j] = (_Float16)s[j];
    }
  }
  for (int i = tid; i < 64 * 64; i += NTHR) {  // x0 = zeros, col 61 (= INPUT_SIZE-3) = 1
    const int row = i >> 6, col = i & 63;
    xbuf[row * 72 + col] = (col == 61) ? (_Float16)1.0f : (_Float16)0.0f;
  }

  int phase = 0;
  group_barrier(ctr, &phase);

  // ---------------- time loop ----------------
  for (int t = 0; t < TSTEPS; ++t) {
    // ======== Layer 0: gates = [x | h0_prev] @ W^T ========
    {
      const _Float16* h0rd = hbL(0, (t + 1) & 1);
      f32x4 acc[2][2];
      #pragma unroll
      for (int mt = 0; mt < 2; ++mt)
        #pragma unroll
        for (int nt = 0; nt < 2; ++nt) {
          f32x4 v; v[0] = biasL0[nt]; v[1] = biasL0[nt]; v[2] = biasL0[nt]; v[3] = biasL0[nt];
          acc[mt][nt] = v;
        }
      #pragma unroll
      for (int kt = 0; kt < 10; ++kt) {
        half8 a[2];
        #pragma unroll
        for (int mt = 0; mt < 2; ++mt) {
          const int m = mi * 32 + mt * 16 + u;  // A-frag: m = lane&15
          if (kt < 2) a[mt] = *(const half8*)(xbuf + m * 72 + kt * 32 + q * 8);
          else        a[mt] = *(const half8*)(h0rd + (size_t)m * 256 + (kt * 32 - 64) + q * 8);
        }
        #pragma unroll
        for (int mt = 0; mt < 2; ++mt)
          #pragma unroll
          for (int nt = 0; nt < 2; ++nt)
            acc[mt][nt] = __builtin_amdgcn_mfma_f32_16x16x32_f16(a[mt], bL0[nt][kt], acc[mt][nt], 0, 0, 0);
      }
      if (ni == 0) {  // u0 = sigmoid(i)*tanh(g), in-lane (tile0=i, tile1=g)
        #pragma unroll
        for (int mt = 0; mt < 2; ++mt)
          #pragma unroll
          for (int r = 0; r < 4; ++r)
            exch[(mi * 8 + mt * 4 + r) * 64 + lane] = sigm(acc[mt][0][r]) * tanh_f(acc[mt][1][r]);
      }
      __syncthreads();
      if (ni == 1) {  // tile0=f, tile1=o
        _Float16* h0wr = hbL(0, t & 1);
        #pragma unroll
        for (int mt = 0; mt < 2; ++mt)
          #pragma unroll
          for (int r = 0; r < 4; ++r) {
            const float u0 = exch[(mi * 8 + mt * 4 + r) * 64 + lane];
            const float cn = sigm(acc[mt][0][r]) * c0st[mt][r] + u0;
            c0st[mt][r] = cn;
            const float hh = sigm(acc[mt][1][r]) * tanh_f(cn);
            h0sv[mt][r] = hh;
            h0wr[(size_t)(mi * 32 + mt * 16 + q * 4 + r) * 256 + w * 16 + u] = (_Float16)hh;
          }
      }
    }
    group_barrier(ctr, &phase);

    // ======== Layer 1: gates = [h0_new | h1_prev] @ W^T ========
    {
      const _Float16* h0nw = hbL(0, t & 1);
      const _Float16* h1rd = hbL(1, (t + 1) & 1);
      f32x4 acc[2][2];
      #pragma unroll
      for (int mt = 0; mt < 2; ++mt)
        #pragma unroll
        for (int nt = 0; nt < 2; ++nt) {
          f32x4 v; v[0] = biasL1[nt]; v[1] = biasL1[nt]; v[2] = biasL1[nt]; v[3] = biasL1[nt];
          acc[mt][nt] = v;
        }
      #pragma unroll
      for (int kt = 0; kt < 16; ++kt) {
        half8 a[2];
        #pragma unroll
        for (int mt = 0; mt < 2; ++mt) {
          const int m = mi * 32 + mt * 16 + u;
          if (kt < 8) a[mt] = *(const half8*)(h0nw + (size_t)m * 256 + kt * 32 + q * 8);
          else        a[mt] = *(const half8*)(h1rd + (size_t)m * 256 + (kt - 8) * 32 + q * 8);
        }
        #pragma unroll
        for (int mt = 0; mt < 2; ++mt)
          #pragma unroll
          for (int nt = 0; nt < 2; ++nt)
            acc[mt][nt] = __builtin_amdgcn_mfma_f32_16x16x32_f16(a[mt], bL1[nt][kt], acc[mt][nt], 0, 0, 0);
      }
      if (ni == 0) {
        #pragma unroll
        for (int mt = 0; mt < 2; ++mt)
          #pragma unroll
          for (int r = 0; r < 4; ++r)
            exch[(mi * 8 + mt * 4 + r) * 64 + lane] = sigm(acc[mt][0][r]) * tanh_f(acc[mt][1][r]);
      }
      __syncthreads();
      if (ni == 1) {
        _Float16* h1wr = hbL(1, t & 1);
        #pragma unroll
        for (int mt = 0; mt < 2; ++mt)
          #pragma unroll
          for (int r = 0; r < 4; ++r) {
            const float u0 = exch[(mi * 8 + mt * 4 + r) * 64 + lane];
            const float cn = sigm(acc[mt][0][r]) * c1st[mt][r] + u0;
            c1st[mt][r] = cn;
            const float hh = sigm(acc[mt][1][r]) * tanh_f(cn);
            h1sv[mt][r] = hh;
            h1wr[(size_t)(mi * 32 + mt * 16 + q * 4 + r) * 256 + w * 16 + u] = (_Float16)hh;
          }
      }
    }
    group_barrier(ctr, &phase);

    // ======== FC + log_softmax (computed redundantly per WG) ========
    {
      const _Float16* h1nw = hbL(1, t & 1);
      f32x4 acc[2][2];
      #pragma unroll
      for (int mt = 0; mt < 2; ++mt)
        #pragma unroll
        for (int nt = 0; nt < 2; ++nt) {
          f32x4 v; v[0] = biasFC[nt]; v[1] = biasFC[nt]; v[2] = biasFC[nt]; v[3] = biasFC[nt];
          acc[mt][nt] = v;
        }
      #pragma unroll
      for (int kt = 0; kt < 8; ++kt) {
        half8 a[2];
        #pragma unroll
        for (int mt = 0; mt < 2; ++mt) {
          const int m = mi * 32 + mt * 16 + u;
          a[mt] = *(const half8*)(h1nw + (size_t)m * 256 + kt * 32 + q * 8);
        }
        #pragma unroll
        for (int mt = 0; mt < 2; ++mt)
          #pragma unroll
          for (int nt = 0; nt < 2; ++nt)
            acc[mt][nt] = __builtin_amdgcn_mfma_f32_16x16x32_f16(a[mt], bFC[nt][kt], acc[mt][nt], 0, 0, 0);
      }
      #pragma unroll
      for (int mt = 0; mt < 2; ++mt)
        #pragma unroll
        for (int nt = 0; nt < 2; ++nt)
          #pragma unroll
          for (int r = 0; r < 4; ++r)
            predbuf[(mi * 32 + mt * 16 + q * 4 + r) * 68 + ni * 32 + nt * 16 + u] = acc[mt][nt][r];
    }
    __syncthreads();
    {
      const int row = tid >> 2;   // group-local chain
      const int cg  = tid & 3;    // 16-col group
      const float* pr = predbuf + row * 68 + cg * 16;
      float p[16];
      #pragma unroll
      for (int j = 0; j < 16; ++j) p[j] = pr[j];
      float mx = -3.0e38f;
      #pragma unroll
      for (int j = 0; j < 16; ++j)
        if (!(cg == 3 && j == 15)) mx = fmaxf(mx, p[j]);   // exclude col 63 (dur)
      mx = fmaxf(mx, __shfl_xor(mx, 1));
      mx = fmaxf(mx, __shfl_xor(mx, 2));
      float sm = 0.0f;
      #pragma unroll
      for (int j = 0; j < 16; ++j)
        if (!(cg == 3 && j == 15)) sm += __expf(p[j] - mx);
      sm += __shfl_xor(sm, 1);
      sm += __shfl_xor(sm, 2);
      const float lz = mx + __logf(sm);
      float o[16];
      #pragma unroll
      for (int j = 0; j < 16; ++j) o[j] = p[j] - lz;
      if (cg == 3) o[15] = sigm(p[15]);                    // duration = sigmoid(pred[63])
      _Float16* xw = xbuf + row * 72 + cg * 16;            // feedback x = out (f16)
      #pragma unroll
      for (int j = 0; j < 16; ++j) xw[j] = (_Float16)o[j];
      if ((row >> 2) == w) {                               // each WG writes 4 of the 64 rows
        const int ch = g * 64 + row;
        float* dst = out + ((size_t)ch * TSTEPS + t) * 64 + cg * 16;
        #pragma unroll
        for (int j = 0; j < 16; ++j) dst[j] = o[j];
      }
    }
    __syncthreads();
  }

  // ---------------- final h_f, c_f ----------------
  if (ni == 1) {
    float* hf = out + OUT_ELEMS;
    float* cf = out + OUT_ELEMS + HF_ELEMS;
    #pragma unroll
    for (int mt = 0; mt < 2; ++mt)
      #pragma unroll
      for (int r = 0; r < 4; ++r) {
        const int ch = g * 64 + mi * 32 + mt * 16 + q * 4 + r;
        const size_t idx = (size_t)ch * 256 + w * 16 + u;
        hf[idx] = h0sv[mt][r];
        hf[262144 + idx] = h1sv[mt][r];
        cf[idx] = c0st[mt][r];
        cf[262144 + idx] = c1st[mt][r];
      }
  }
}

extern "C" void kernel_launch(void* const* d_in, const int* in_sizes, int n_in,
                              void* d_out, int out_size, void* d_ws, size_t ws_size,
                              hipStream_t stream) {
  (void)in_sizes; (void)n_in; (void)out_size;
  if (ws_size < (size_t)WS_NEEDED) return;

  const float* h0   = (const float*)d_in[1];
  const float* c0   = (const float*)d_in[2];
  const float* Wih0 = (const float*)d_in[3];
  const float* Whh0 = (const float*)d_in[4];
  const float* bih0 = (const float*)d_in[5];
  const float* bhh0 = (const float*)d_in[6];
  const float* Wih1 = (const float*)d_in[7];
  const float* Whh1 = (const float*)d_in[8];
  const float* bih1 = (const float*)d_in[9];
  const float* bhh1 = (const float*)d_in[10];
  const float* Wfc  = (const float*)d_in[11];
  const float* bfc  = (const float*)d_in[12];
  float* outp = (float*)d_out;
  char*  wsp  = (char*)d_ws;

  // zero barrier counters (ws is re-poisoned to 0xAA before every launch)
  hipMemsetAsync(d_ws, 0, WS_HBUF_OFF, stream);

  void* args[] = { &h0, &c0, &Wih0, &Whh0, &bih0, &bhh0, &Wih1, &Whh1,
                   &bih1, &bhh1, &Wfc, &bfc, &outp, &wsp };
  hipError_t e = hipLaunchCooperativeKernel((const void*)decoder_kernel,
                                            dim3(NGROUP * GWG), dim3(NTHR),
                                            args, 0u, stream);
  if (e != hipSuccess) {
    // fallback: plain launch (256 blocks at 1 WG/CU are co-resident on 256 CUs)
    decoder_kernel<<<dim3(NGROUP * GWG), dim3(NTHR), 0, stream>>>(
        h0, c0, Wih0, Whh0, bih0, bhh0, Wih1, Whh1, bih1, bhh1, Wfc, bfc, outp, wsp);
  }
}

// Round 3
// 6566.302 us; speedup vs baseline: 2.5327x; 2.5327x over previous
//
#include <hip/hip_runtime.h>
#include <stdint.h>
#include <stddef.h>

// Persistent 2-layer LSTM decoder, B=1024, H=256, T=512.
// 16 groups x 16 WGs x 256 threads. WG owns 16 hidden units (both layers),
// weights register-resident as f16 MFMA B-fragments. 2 group barriers/step.
//
// R2: all cross-WG data goes through the memory-side coherent point (IF$):
//   - h-buffer writes: relaxed agent-scope atomic stores (write-through, sc1)
//   - h-buffer reads:  relaxed agent-scope atomic loads (L1/L2 bypass)
//   - barrier: device-scope atomicAdd + agent-scope atomic poll (R0-proven),
//     NO __threadfence (R0: its buffer_wbl2/inv sc1 L2-walks cost 30us/step),
//     NO workgroup-scope spin (R1: InstCombine turns fetch_add(p,0) into an
//     atomic load; workgroup scope lets it hit L1 -> stale spin -> hang).
// Correctness no longer depends on workgroup->XCD placement.
//
// h-buffer layout (per group, per layer, per parity): chunked f16
//   f16_index = (c*64 + m)*8 + e   where c = k/8 (0..31), m = row, e = k%8
// so an MFMA A-fragment (8 consecutive k for one m) is one 16B chunk.

#define NGROUP 16
#define GWG    16
#define NTHR   256
#define TSTEPS 512

typedef _Float16 half8 __attribute__((ext_vector_type(8)));
typedef float    f32x4 __attribute__((ext_vector_type(4)));

#define OUT_ELEMS   33554432   // 1024*512*64
#define HF_ELEMS    524288     // 2*1024*256
#define HBUF_ELEMS  16384      // 64*256 (f16) per layer/parity
#define GROUP_WS_BYTES 131072  // 4 bufs * 16384 * 2B
#define WS_HBUF_OFF 4096
#define WS_NEEDED   (WS_HBUF_OFF + NGROUP * GROUP_WS_BYTES)

__device__ __forceinline__ float sigm(float x)   { return 1.0f / (1.0f + __expf(-x)); }
__device__ __forceinline__ float tanh_f(float x) { return 1.0f - 2.0f / (__expf(2.0f * x) + 1.0f); }

// Group barrier via the coherent point. __syncthreads before the arrive emits
// s_waitcnt vmcnt(0): our agent-scope (write-through) stores have reached IF$
// before the counter bumps. Poll is an agent-scope load: bypasses L1/L2, reads
// IF$ directly. No cache maintenance needed anywhere.
__device__ __forceinline__ void group_barrier(int* ctr, int* phase) {
  __syncthreads();
  if (threadIdx.x == 0) {
    atomicAdd(ctr, 1);   // device-scope RMW at the coherent point (m20)
    const int target = GWG * (++(*phase));
    while (__hip_atomic_load(ctr, __ATOMIC_RELAXED, __HIP_MEMORY_SCOPE_AGENT) < target)
      __builtin_amdgcn_s_sleep(1);
  }
  __syncthreads();
}

// 16B A-fragment load from a chunked h-buffer via 2 x 8B agent atomic loads.
__device__ __forceinline__ half8 ld_frag(const _Float16* buf, int idx16) {
  const uint64_t* p = (const uint64_t*)buf + (size_t)idx16 * 2;
  union { uint64_t u[2]; half8 v; } x;
  x.u[0] = __hip_atomic_load(p,     __ATOMIC_RELAXED, __HIP_MEMORY_SCOPE_AGENT);
  x.u[1] = __hip_atomic_load(p + 1, __ATOMIC_RELAXED, __HIP_MEMORY_SCOPE_AGENT);
  return x.v;
}

// Packed f16x2 agent store of (col u, col u+1) for row mh. Even-u lanes only.
__device__ __forceinline__ void store_h_pair(_Float16* hw, int w, int u, int mh,
                                             float lo, float hi) {
  union { _Float16 h[2]; uint32_t u32; } pk;
  pk.h[0] = (_Float16)lo; pk.h[1] = (_Float16)hi;
  const int c = w * 2 + (u >> 3);
  __hip_atomic_store((uint32_t*)hw + (size_t)(c * 64 + mh) * 4 + ((u & 7) >> 1),
                     pk.u32, __ATOMIC_RELAXED, __HIP_MEMORY_SCOPE_AGENT);
}

__global__ __launch_bounds__(NTHR, 1)
void decoder_kernel(const float* __restrict__ h0in, const float* __restrict__ c0in,
                    const float* __restrict__ Wih0, const float* __restrict__ Whh0,
                    const float* __restrict__ bih0, const float* __restrict__ bhh0,
                    const float* __restrict__ Wih1, const float* __restrict__ Whh1,
                    const float* __restrict__ bih1, const float* __restrict__ bhh1,
                    const float* __restrict__ Wfc,  const float* __restrict__ bfc,
                    float* __restrict__ out, char* __restrict__ ws)
{
  const int tid  = threadIdx.x;
  const int lane = tid & 63;
  const int wave = tid >> 6;
  const int mi   = wave >> 1;   // M half (32 chains)
  const int ni   = wave & 1;    // N half: ni=0 -> {i,g}, ni=1 -> {f,o}
  const int q    = lane >> 4;   // quad
  const int u    = lane & 15;   // unit-in-slice / frag col / frag m

  // Swizzle kept for fabric locality; correctness does not depend on it.
  const int b = blockIdx.x;
  const int g = (b & 7) * 2 + ((b >> 3) >> 4);  // group 0..15
  const int w = (b >> 3) & 15;                  // member 0..15 (unit slice)

  int* ctr = (int*)(ws + (size_t)g * 128);
  _Float16* hb_base = (_Float16*)(ws + WS_HBUF_OFF + (size_t)g * GROUP_WS_BYTES);
  auto hbL = [&](int layer, int par) { return hb_base + (size_t)(layer * 2 + par) * HBUF_ELEMS; };

  __shared__ __align__(16) _Float16 xbuf[64 * 72];   // 72-elem stride (bank pad)
  __shared__ __align__(16) float    exch[2 * 8 * 64];
  __shared__ __align__(16) float    predbuf[64 * 68];

  // ---------------- weight fragments (register-resident, f16) ----------------
  // gates = act @ W^T : A[m=chain][k], B[k][n=gate-row].  B-frag: n=lane&15, k=q*8+j.
  half8 bL0[2][10]; half8 bL1[2][16]; half8 bFC[2][8];
  float biasL0[2], biasL1[2], biasFC[2];
  #pragma unroll
  for (int nt = 0; nt < 2; ++nt) {
    // gate-type base: ni=0 tiles {i(0), g(512)}, ni=1 tiles {f(256), o(768)}
    const int base0 = (ni == 0) ? (nt == 0 ? 0 : 512) : (nt == 0 ? 256 : 768);
    const int row = base0 + w * 16 + u;
    biasL0[nt] = bih0[row] + bhh0[row];
    biasL1[nt] = bih1[row] + bhh1[row];
    #pragma unroll
    for (int kt = 0; kt < 10; ++kt) {   // L0: K = 64(x) + 256(h0)
      const int k0 = kt * 32 + q * 8;
      const float* src = (kt < 2) ? (Wih0 + (size_t)row * 64 + k0)
                                  : (Whh0 + (size_t)row * 256 + (k0 - 64));
      half8 v;
      #pragma unroll
      for (int j = 0; j < 8; ++j) v[j] = (_Float16)src[j];
      bL0[nt][kt] = v;
    }
    #pragma unroll
    for (int kt = 0; kt < 16; ++kt) {   // L1: K = 256(h0new) + 256(h1)
      const int k0 = kt * 32 + q * 8;
      const float* src = (kt < 8) ? (Wih1 + (size_t)row * 256 + k0)
                                  : (Whh1 + (size_t)row * 256 + (k0 - 256));
      half8 v;
      #pragma unroll
      for (int j = 0; j < 8; ++j) v[j] = (_Float16)src[j];
      bL1[nt][kt] = v;
    }
    const int rowF = ni * 32 + nt * 16 + u;  // FC: no reorder
    biasFC[nt] = bfc[rowF];
    #pragma unroll
    for (int kt = 0; kt < 8; ++kt) {
      const float* src = Wfc + (size_t)rowF * 256 + kt * 32 + q * 8;
      half8 v;
      #pragma unroll
      for (int j = 0; j < 8; ++j) v[j] = (_Float16)src[j];
      bFC[nt][kt] = v;
    }
  }

  // ---------------- state init ----------------
  float c0st[2][4], c1st[2][4], h0sv[2][4], h1sv[2][4];
  #pragma unroll
  for (int mt = 0; mt < 2; ++mt)
    #pragma unroll
    for (int r = 0; r < 4; ++r) { c0st[mt][r] = 0; c1st[mt][r] = 0; h0sv[mt][r] = 0; h1sv[mt][r] = 0; }
  if (ni == 1) {  // ni=1 waves own c-state in D-frag layout
    #pragma unroll
    for (int mt = 0; mt < 2; ++mt)
      #pragma unroll
      for (int r = 0; r < 4; ++r) {
        const int ch = g * 64 + mi * 32 + mt * 16 + q * 4 + r;
        c0st[mt][r] = c0in[(size_t)ch * 256 + w * 16 + u];
        c1st[mt][r] = c0in[262144 + (size_t)ch * 256 + w * 16 + u];
      }
  }
  {  // initial h -> parity-1 chunked buffers, agent-scope 8B stores
    const int gi = tid * 4;             // 4 consecutive f16 per thread (1024 per WG slice)
    const int e0 = gi & 7;              // 0 or 4
    const int m  = (gi >> 3) & 63;
    const int cc = gi >> 9;             // 0 or 1
    const int c  = w * 2 + cc;
    const int col = c * 8 + e0;         // global hidden-unit column
    #pragma unroll
    for (int l = 0; l < 2; ++l) {
      const float* s = h0in + (size_t)l * 262144 + (size_t)(g * 64 + m) * 256 + col;
      union { _Float16 h[4]; uint64_t u64; } pk;
      #pragma unroll
      for (int j = 0; j < 4; ++j) pk.h[j] = (_Float16)s[j];
      __hip_atomic_store((uint64_t*)hbL(l, 1) + ((size_t)(c * 64 + m) * 2 + (e0 >> 2)),
                         pk.u64, __ATOMIC_RELAXED, __HIP_MEMORY_SCOPE_AGENT);
    }
  }
  for (int i = tid; i < 64 * 64; i += NTHR) {  // x0 = zeros, col 61 (= INPUT_SIZE-3) = 1
    const int row = i >> 6, col = i & 63;
    xbuf[row * 72 + col] = (col == 61) ? (_Float16)1.0f : (_Float16)0.0f;
  }

  int phase = 0;
  group_barrier(ctr, &phase);

  // ---------------- time loop ----------------
  for (int t = 0; t < TSTEPS; ++t) {
    // ======== Layer 0: gates = [x | h0_prev] @ W^T ========
    {
      const _Float16* h0rd = hbL(0, (t + 1) & 1);
      f32x4 acc[2][2];
      #pragma unroll
      for (int mt = 0; mt < 2; ++mt)
        #pragma unroll
        for (int nt = 0; nt < 2; ++nt) {
          f32x4 v; v[0] = biasL0[nt]; v[1] = biasL0[nt]; v[2] = biasL0[nt]; v[3] = biasL0[nt];
          acc[mt][nt] = v;
        }
      #pragma unroll
      for (int kt = 0; kt < 10; ++kt) {
        half8 a[2];
        #pragma unroll
        for (int mt = 0; mt < 2; ++mt) {
          const int m = mi * 32 + mt * 16 + u;  // A-frag: m = lane&15
          if (kt < 2) a[mt] = *(const half8*)(xbuf + m * 72 + kt * 32 + q * 8);
          else        a[mt] = ld_frag(h0rd, (kt * 4 - 8 + q) * 64 + m);
        }
        #pragma unroll
        for (int mt = 0; mt < 2; ++mt)
          #pragma unroll
          for (int nt = 0; nt < 2; ++nt)
            acc[mt][nt] = __builtin_amdgcn_mfma_f32_16x16x32_f16(a[mt], bL0[nt][kt], acc[mt][nt], 0, 0, 0);
      }
      if (ni == 0) {  // u0 = sigmoid(i)*tanh(g), in-lane (tile0=i, tile1=g)
        #pragma unroll
        for (int mt = 0; mt < 2; ++mt)
          #pragma unroll
          for (int r = 0; r < 4; ++r)
            exch[(mi * 8 + mt * 4 + r) * 64 + lane] = sigm(acc[mt][0][r]) * tanh_f(acc[mt][1][r]);
      }
      __syncthreads();
      if (ni == 1) {  // tile0=f, tile1=o
        _Float16* h0wr = hbL(0, t & 1);
        float hv[2][4];
        #pragma unroll
        for (int mt = 0; mt < 2; ++mt)
          #pragma unroll
          for (int r = 0; r < 4; ++r) {
            const float u0 = exch[(mi * 8 + mt * 4 + r) * 64 + lane];
            const float cn = sigm(acc[mt][0][r]) * c0st[mt][r] + u0;
            c0st[mt][r] = cn;
            const float hh = sigm(acc[mt][1][r]) * tanh_f(cn);
            h0sv[mt][r] = hh;
            hv[mt][r] = hh;
          }
        #pragma unroll
        for (int mt = 0; mt < 2; ++mt)
          #pragma unroll
          for (int r = 0; r < 4; ++r) {
            const float other = __shfl_xor(hv[mt][r], 1);
            if (!(u & 1))
              store_h_pair(h0wr, w, u, mi * 32 + mt * 16 + q * 4 + r, hv[mt][r], other);
          }
      }
    }
    group_barrier(ctr, &phase);

    // ======== Layer 1: gates = [h0_new | h1_prev] @ W^T ========
    {
      const _Float16* h0nw = hbL(0, t & 1);
      const _Float16* h1rd = hbL(1, (t + 1) & 1);
      f32x4 acc[2][2];
      #pragma unroll
      for (int mt = 0; mt < 2; ++mt)
        #pragma unroll
        for (int nt = 0; nt < 2; ++nt) {
          f32x4 v; v[0] = biasL1[nt]; v[1] = biasL1[nt]; v[2] = biasL1[nt]; v[3] = biasL1[nt];
          acc[mt][nt] = v;
        }
      #pragma unroll
      for (int kt = 0; kt < 16; ++kt) {
        half8 a[2];
        #pragma unroll
        for (int mt = 0; mt < 2; ++mt) {
          const int m = mi * 32 + mt * 16 + u;
          if (kt < 8) a[mt] = ld_frag(h0nw, (kt * 4 + q) * 64 + m);
          else        a[mt] = ld_frag(h1rd, ((kt - 8) * 4 + q) * 64 + m);
        }
        #pragma unroll
        for (int mt = 0; mt < 2; ++mt)
          #pragma unroll
          for (int nt = 0; nt < 2; ++nt)
            acc[mt][nt] = __builtin_amdgcn_mfma_f32_16x16x32_f16(a[mt], bL1[nt][kt], acc[mt][nt], 0, 0, 0);
      }
      if (ni == 0) {
        #pragma unroll
        for (int mt = 0; mt < 2; ++mt)
          #pragma unroll
          for (int r = 0; r < 4; ++r)
            exch[(mi * 8 + mt * 4 + r) * 64 + lane] = sigm(acc[mt][0][r]) * tanh_f(acc[mt][1][r]);
      }
      __syncthreads();
      if (ni == 1) {
        _Float16* h1wr = hbL(1, t & 1);
        float hv[2][4];
        #pragma unroll
        for (int mt = 0; mt < 2; ++mt)
          #pragma unroll
          for (int r = 0; r < 4; ++r) {
            const float u0 = exch[(mi * 8 + mt * 4 + r) * 64 + lane];
            const float cn = sigm(acc[mt][0][r]) * c1st[mt][r] + u0;
            c1st[mt][r] = cn;
            const float hh = sigm(acc[mt][1][r]) * tanh_f(cn);
            h1sv[mt][r] = hh;
            hv[mt][r] = hh;
          }
        #pragma unroll
        for (int mt = 0; mt < 2; ++mt)
          #pragma unroll
          for (int r = 0; r < 4; ++r) {
            const float other = __shfl_xor(hv[mt][r], 1);
            if (!(u & 1))
              store_h_pair(h1wr, w, u, mi * 32 + mt * 16 + q * 4 + r, hv[mt][r], other);
          }
      }
    }
    group_barrier(ctr, &phase);

    // ======== FC + log_softmax (computed redundantly per WG) ========
    {
      const _Float16* h1nw = hbL(1, t & 1);
      f32x4 acc[2][2];
      #pragma unroll
      for (int mt = 0; mt < 2; ++mt)
        #pragma unroll
        for (int nt = 0; nt < 2; ++nt) {
          f32x4 v; v[0] = biasFC[nt]; v[1] = biasFC[nt]; v[2] = biasFC[nt]; v[3] = biasFC[nt];
          acc[mt][nt] = v;
        }
      #pragma unroll
      for (int kt = 0; kt < 8; ++kt) {
        half8 a[2];
        #pragma unroll
        for (int mt = 0; mt < 2; ++mt) {
          const int m = mi * 32 + mt * 16 + u;
          a[mt] = ld_frag(h1nw, (kt * 4 + q) * 64 + m);
        }
        #pragma unroll
        for (int mt = 0; mt < 2; ++mt)
          #pragma unroll
          for (int nt = 0; nt < 2; ++nt)
            acc[mt][nt] = __builtin_amdgcn_mfma_f32_16x16x32_f16(a[mt], bFC[nt][kt], acc[mt][nt], 0, 0, 0);
      }
      #pragma unroll
      for (int mt = 0; mt < 2; ++mt)
        #pragma unroll
        for (int nt = 0; nt < 2; ++nt)
          #pragma unroll
          for (int r = 0; r < 4; ++r)
            predbuf[(mi * 32 + mt * 16 + q * 4 + r) * 68 + ni * 32 + nt * 16 + u] = acc[mt][nt][r];
    }
    __syncthreads();
    {
      const int row = tid >> 2;   // group-local chain
      const int cg  = tid & 3;    // 16-col group
      const float* pr = predbuf + row * 68 + cg * 16;
      float p[16];
      #pragma unroll
      for (int j = 0; j < 16; ++j) p[j] = pr[j];
      float mx = -3.0e38f;
      #pragma unroll
      for (int j = 0; j < 16; ++j)
        if (!(cg == 3 && j == 15)) mx = fmaxf(mx, p[j]);   // exclude col 63 (dur)
      mx = fmaxf(mx, __shfl_xor(mx, 1));
      mx = fmaxf(mx, __shfl_xor(mx, 2));
      float sm = 0.0f;
      #pragma unroll
      for (int j = 0; j < 16; ++j)
        if (!(cg == 3 && j == 15)) sm += __expf(p[j] - mx);
      sm += __shfl_xor(sm, 1);
      sm += __shfl_xor(sm, 2);
      const float lz = mx + __logf(sm);
      float o[16];
      #pragma unroll
      for (int j = 0; j < 16; ++j) o[j] = p[j] - lz;
      if (cg == 3) o[15] = sigm(p[15]);                    // duration = sigmoid(pred[63])
      _Float16* xw = xbuf + row * 72 + cg * 16;            // feedback x = out (f16)
      #pragma unroll
      for (int j = 0; j < 16; ++j) xw[j] = (_Float16)o[j];
      if ((row >> 2) == w) {                               // each WG writes 4 of the 64 rows
        const int ch = g * 64 + row;
        float* dst = out + ((size_t)ch * TSTEPS + t) * 64 + cg * 16;
        #pragma unroll
        for (int j = 0; j < 16; ++j) dst[j] = o[j];
      }
    }
    __syncthreads();
  }

  // ---------------- final h_f, c_f ----------------
  if (ni == 1) {
    float* hf = out + OUT_ELEMS;
    float* cf = out + OUT_ELEMS + HF_ELEMS;
    #pragma unroll
    for (int mt = 0; mt < 2; ++mt)
      #pragma unroll
      for (int r = 0; r < 4; ++r) {
        const int ch = g * 64 + mi * 32 + mt * 16 + q * 4 + r;
        const size_t idx = (size_t)ch * 256 + w * 16 + u;
        hf[idx] = h0sv[mt][r];
        hf[262144 + idx] = h1sv[mt][r];
        cf[idx] = c0st[mt][r];
        cf[262144 + idx] = c1st[mt][r];
      }
  }
}

extern "C" void kernel_launch(void* const* d_in, const int* in_sizes, int n_in,
                              void* d_out, int out_size, void* d_ws, size_t ws_size,
                              hipStream_t stream) {
  (void)in_sizes; (void)n_in; (void)out_size;
  if (ws_size < (size_t)WS_NEEDED) return;

  const float* h0   = (const float*)d_in[1];
  const float* c0   = (const float*)d_in[2];
  const float* Wih0 = (const float*)d_in[3];
  const float* Whh0 = (const float*)d_in[4];
  const float* bih0 = (const float*)d_in[5];
  const float* bhh0 = (const float*)d_in[6];
  const float* Wih1 = (const float*)d_in[7];
  const float* Whh1 = (const float*)d_in[8];
  const float* bih1 = (const float*)d_in[9];
  const float* bhh1 = (const float*)d_in[10];
  const float* Wfc  = (const float*)d_in[11];
  const float* bfc  = (const float*)d_in[12];
  float* outp = (float*)d_out;
  char*  wsp  = (char*)d_ws;

  // zero barrier counters (ws is re-poisoned to 0xAA before every launch)
  hipMemsetAsync(d_ws, 0, WS_HBUF_OFF, stream);

  void* args[] = { &h0, &c0, &Wih0, &Whh0, &bih0, &bhh0, &Wih1, &Whh1,
                   &bih1, &bhh1, &Wfc, &bfc, &outp, &wsp };
  hipError_t e = hipLaunchCooperativeKernel((const void*)decoder_kernel,
                                            dim3(NGROUP * GWG), dim3(NTHR),
                                            args, 0u, stream);
  if (e != hipSuccess) {
    // fallback: plain launch (256 blocks at 1 WG/CU are co-resident on 256 CUs)
    decoder_kernel<<<dim3(NGROUP * GWG), dim3(NTHR), 0, stream>>>(
        h0, c0, Wih0, Whh0, bih0, bhh0, Wih1, Whh1, bih1, bhh1, Wfc, bfc, outp, wsp);
  }
}

// Round 4
// 5204.002 us; speedup vs baseline: 3.1957x; 1.2618x over previous
//
#include <hip/hip_runtime.h>
#include <stdint.h>
#include <stddef.h>

// Persistent 2-layer LSTM decoder, B=1024, H=256, T=512.
// 16 groups x 16 WGs x 256 threads. WG owns 16 hidden units (both layers),
// weights register-resident as f16 MFMA B-fragments. 2 group barriers/step.
//
// R4: XCD-local data path.
//  - Groups are formed from the PHYSICAL XCD id (s_getreg HW_REG_XCC_ID, m09)
//    + a startup slot-claim atomic: 256 full-CU blocks on 256 CUs => exactly
//    32 blocks/XCD => 2 groups/XCD by construction. No dispatch assumptions.
//  - h-buffers: plain stores (write-through L1 -> XCD L2; vmcnt(0) at
//    __syncthreads = release to L2) and plain loads; readers invalidate L1
//    only (buffer_inv sc0) at the barrier. No L2 walks, no IF$ round trips.
//    (R3 used agent-scope L1/L2-bypass loads: 64MB/step from IF$ fabric at
//    ~900cy => 12.8us/step. R0 used __threadfence: full L2 wb+inv walks =>
//    32.5us/step.)
//  - Barrier: workgroup-scope atomic RMWs (execute at the XCD L2, ~250cy).
//    Poll adds an asm-opaque zero so InstCombine cannot fold the RMW into a
//    (L1-cacheable, stale) load — that fold is what hung R1.
//
// h-buffer layout (per group, per layer, per parity): chunked f16
//   f16_index = (c*64 + m)*8 + e   where c = k/8 (0..31), m = row, e = k%8
// so an MFMA A-fragment (8 consecutive k for one m) is one 16B chunk.

#define NGROUP 16
#define GWG    16
#define NTHR   256
#define TSTEPS 512

typedef _Float16 half8 __attribute__((ext_vector_type(8)));
typedef float    f32x4 __attribute__((ext_vector_type(4)));

#define OUT_ELEMS   33554432   // 1024*512*64
#define HF_ELEMS    524288     // 2*1024*256
#define HBUF_ELEMS  16384      // 64*256 (f16) per layer/parity
#define GROUP_WS_BYTES 131072  // 4 bufs * 16384 * 2B
#define WS_HBUF_OFF 4096
#define WS_NEEDED   (WS_HBUF_OFF + NGROUP * GROUP_WS_BYTES)

__device__ __forceinline__ float sigm(float x)   { return 1.0f / (1.0f + __expf(-x)); }
__device__ __forceinline__ float tanh_f(float x) { return 1.0f - 2.0f / (__expf(2.0f * x) + 1.0f); }

// XCD-local group barrier. All 16 member WGs are on one XCD by construction
// (groups derived from HW_REG_XCC_ID). Stores are in the XCD L2 when each
// wave's pre-s_barrier s_waitcnt vmcnt(0) retires (write-through L1).
// Arrive/poll are real RMWs at the L2 (zz = opaque zero defeats the
// atomicrmw-add-0 -> load fold). Acquire = L1 invalidate only.
__device__ __forceinline__ void group_barrier(int* ctr, int* phase, int zz) {
  __syncthreads();
  if (threadIdx.x == 0) {
    __hip_atomic_fetch_add(ctr, 1, __ATOMIC_RELEASE, __HIP_MEMORY_SCOPE_WORKGROUP);
    const int target = GWG * (++(*phase));
    while (__hip_atomic_fetch_add(ctr, zz, __ATOMIC_RELAXED, __HIP_MEMORY_SCOPE_WORKGROUP) < target)
      __builtin_amdgcn_s_sleep(1);
    asm volatile("buffer_inv sc0" ::: "memory");   // L1-only invalidate (gfx940+)
  }
  __syncthreads();
}

// 16B A-fragment plain load from a chunked h-buffer (L1/L2-cached).
__device__ __forceinline__ half8 ld_frag(const _Float16* buf, int idx16) {
  return *(const half8*)(buf + (size_t)idx16 * 8);
}

// Packed f16x2 plain store of (col u, col u+1) for row mh. Even-u lanes only.
__device__ __forceinline__ void store_h_pair(_Float16* hw, int w, int u, int mh,
                                             float lo, float hi) {
  union { _Float16 h[2]; uint32_t u32; } pk;
  pk.h[0] = (_Float16)lo; pk.h[1] = (_Float16)hi;
  const int c = w * 2 + (u >> 3);
  *((uint32_t*)hw + (size_t)(c * 64 + mh) * 4 + ((u & 7) >> 1)) = pk.u32;
}

__global__ __launch_bounds__(NTHR, 1)
void decoder_kernel(const float* __restrict__ h0in, const float* __restrict__ c0in,
                    const float* __restrict__ Wih0, const float* __restrict__ Whh0,
                    const float* __restrict__ bih0, const float* __restrict__ bhh0,
                    const float* __restrict__ Wih1, const float* __restrict__ Whh1,
                    const float* __restrict__ bih1, const float* __restrict__ bhh1,
                    const float* __restrict__ Wfc,  const float* __restrict__ bfc,
                    float* __restrict__ out, char* __restrict__ ws)
{
  const int tid  = threadIdx.x;
  const int lane = tid & 63;
  const int wave = tid >> 6;
  const int mi   = wave >> 1;   // M half (32 chains)
  const int ni   = wave & 1;    // N half: ni=0 -> {i,g}, ni=1 -> {f,o}
  const int q    = lane >> 4;   // quad
  const int u    = lane & 15;   // unit-in-slice / frag col / frag m

  // Opaque zero: an SGPR the compiler cannot constant-fold.
  int zz;
  asm volatile("s_mov_b32 %0, 0" : "=s"(zz));

  // ---- derive (group g, member w) from the physical XCD id ----
  __shared__ int s_gw[2];
  if (tid == 0) {
    uint32_t xcc;
    asm volatile("s_getreg_b32 %0, hwreg(HW_REG_XCC_ID)" : "=s"(xcc));
    xcc &= 7;
    const int slot = atomicAdd((int*)(ws + 2048) + (size_t)xcc * 32, 1);  // device-scope, once
    s_gw[0] = (int)xcc * 2 + (slot >> 4);   // group 0..15 (2 per XCD)
    s_gw[1] = slot & 15;                    // member 0..15 (unit slice)
  }
  __syncthreads();
  const int g = s_gw[0];
  const int w = s_gw[1];

  int* ctr = (int*)(ws + (size_t)g * 128);
  _Float16* hb_base = (_Float16*)(ws + WS_HBUF_OFF + (size_t)g * GROUP_WS_BYTES);
  auto hbL = [&](int layer, int par) { return hb_base + (size_t)(layer * 2 + par) * HBUF_ELEMS; };

  __shared__ __align__(16) _Float16 xbuf[64 * 72];   // 72-elem stride (bank pad)
  __shared__ __align__(16) float    exch[2 * 8 * 64];
  __shared__ __align__(16) float    predbuf[64 * 68];

  // ---------------- weight fragments (register-resident, f16) ----------------
  // gates = act @ W^T : A[m=chain][k], B[k][n=gate-row].  B-frag: n=lane&15, k=q*8+j.
  half8 bL0[2][10]; half8 bL1[2][16]; half8 bFC[2][8];
  float biasL0[2], biasL1[2], biasFC[2];
  #pragma unroll
  for (int nt = 0; nt < 2; ++nt) {
    // gate-type base: ni=0 tiles {i(0), g(512)}, ni=1 tiles {f(256), o(768)}
    const int base0 = (ni == 0) ? (nt == 0 ? 0 : 512) : (nt == 0 ? 256 : 768);
    const int row = base0 + w * 16 + u;
    biasL0[nt] = bih0[row] + bhh0[row];
    biasL1[nt] = bih1[row] + bhh1[row];
    #pragma unroll
    for (int kt = 0; kt < 10; ++kt) {   // L0: K = 64(x) + 256(h0)
      const int k0 = kt * 32 + q * 8;
      const float* src = (kt < 2) ? (Wih0 + (size_t)row * 64 + k0)
                                  : (Whh0 + (size_t)row * 256 + (k0 - 64));
      half8 v;
      #pragma unroll
      for (int j = 0; j < 8; ++j) v[j] = (_Float16)src[j];
      bL0[nt][kt] = v;
    }
    #pragma unroll
    for (int kt = 0; kt < 16; ++kt) {   // L1: K = 256(h0new) + 256(h1)
      const int k0 = kt * 32 + q * 8;
      const float* src = (kt < 8) ? (Wih1 + (size_t)row * 256 + k0)
                                  : (Whh1 + (size_t)row * 256 + (k0 - 256));
      half8 v;
      #pragma unroll
      for (int j = 0; j < 8; ++j) v[j] = (_Float16)src[j];
      bL1[nt][kt] = v;
    }
    const int rowF = ni * 32 + nt * 16 + u;  // FC: no reorder
    biasFC[nt] = bfc[rowF];
    #pragma unroll
    for (int kt = 0; kt < 8; ++kt) {
      const float* src = Wfc + (size_t)rowF * 256 + kt * 32 + q * 8;
      half8 v;
      #pragma unroll
      for (int j = 0; j < 8; ++j) v[j] = (_Float16)src[j];
      bFC[nt][kt] = v;
    }
  }

  // ---------------- state init ----------------
  float c0st[2][4], c1st[2][4], h0sv[2][4], h1sv[2][4];
  #pragma unroll
  for (int mt = 0; mt < 2; ++mt)
    #pragma unroll
    for (int r = 0; r < 4; ++r) { c0st[mt][r] = 0; c1st[mt][r] = 0; h0sv[mt][r] = 0; h1sv[mt][r] = 0; }
  if (ni == 1) {  // ni=1 waves own c-state in D-frag layout
    #pragma unroll
    for (int mt = 0; mt < 2; ++mt)
      #pragma unroll
      for (int r = 0; r < 4; ++r) {
        const int ch = g * 64 + mi * 32 + mt * 16 + q * 4 + r;
        c0st[mt][r] = c0in[(size_t)ch * 256 + w * 16 + u];
        c1st[mt][r] = c0in[262144 + (size_t)ch * 256 + w * 16 + u];
      }
  }
  {  // initial h -> parity-1 chunked buffers, plain 8B stores
    const int gi = tid * 4;             // 4 consecutive f16 per thread
    const int e0 = gi & 7;              // 0 or 4
    const int m  = (gi >> 3) & 63;
    const int cc = gi >> 9;             // 0 or 1
    const int c  = w * 2 + cc;
    const int col = c * 8 + e0;         // global hidden-unit column
    #pragma unroll
    for (int l = 0; l < 2; ++l) {
      const float* s = h0in + (size_t)l * 262144 + (size_t)(g * 64 + m) * 256 + col;
      union { _Float16 h[4]; uint64_t u64; } pk;
      #pragma unroll
      for (int j = 0; j < 4; ++j) pk.h[j] = (_Float16)s[j];
      *((uint64_t*)hbL(l, 1) + ((size_t)(c * 64 + m) * 2 + (e0 >> 2))) = pk.u64;
    }
  }
  for (int i = tid; i < 64 * 64; i += NTHR) {  // x0 = zeros, col 61 (= INPUT_SIZE-3) = 1
    const int row = i >> 6, col = i & 63;
    xbuf[row * 72 + col] = (col == 61) ? (_Float16)1.0f : (_Float16)0.0f;
  }

  int phase = 0;
  group_barrier(ctr, &phase, zz);

  // ---------------- time loop ----------------
  for (int t = 0; t < TSTEPS; ++t) {
    // ======== Layer 0: gates = [x | h0_prev] @ W^T ========
    {
      const _Float16* h0rd = hbL(0, (t + 1) & 1);
      f32x4 acc[2][2];
      #pragma unroll
      for (int mt = 0; mt < 2; ++mt)
        #pragma unroll
        for (int nt = 0; nt < 2; ++nt) {
          f32x4 v; v[0] = biasL0[nt]; v[1] = biasL0[nt]; v[2] = biasL0[nt]; v[3] = biasL0[nt];
          acc[mt][nt] = v;
        }
      #pragma unroll
      for (int kt = 0; kt < 10; ++kt) {
        half8 a[2];
        #pragma unroll
        for (int mt = 0; mt < 2; ++mt) {
          const int m = mi * 32 + mt * 16 + u;  // A-frag: m = lane&15
          if (kt < 2) a[mt] = *(const half8*)(xbuf + m * 72 + kt * 32 + q * 8);
          else        a[mt] = ld_frag(h0rd, (kt * 4 - 8 + q) * 64 + m);
        }
        #pragma unroll
        for (int mt = 0; mt < 2; ++mt)
          #pragma unroll
          for (int nt = 0; nt < 2; ++nt)
            acc[mt][nt] = __builtin_amdgcn_mfma_f32_16x16x32_f16(a[mt], bL0[nt][kt], acc[mt][nt], 0, 0, 0);
      }
      if (ni == 0) {  // u0 = sigmoid(i)*tanh(g), in-lane (tile0=i, tile1=g)
        #pragma unroll
        for (int mt = 0; mt < 2; ++mt)
          #pragma unroll
          for (int r = 0; r < 4; ++r)
            exch[(mi * 8 + mt * 4 + r) * 64 + lane] = sigm(acc[mt][0][r]) * tanh_f(acc[mt][1][r]);
      }
      __syncthreads();
      if (ni == 1) {  // tile0=f, tile1=o
        _Float16* h0wr = hbL(0, t & 1);
        float hv[2][4];
        #pragma unroll
        for (int mt = 0; mt < 2; ++mt)
          #pragma unroll
          for (int r = 0; r < 4; ++r) {
            const float u0 = exch[(mi * 8 + mt * 4 + r) * 64 + lane];
            const float cn = sigm(acc[mt][0][r]) * c0st[mt][r] + u0;
            c0st[mt][r] = cn;
            const float hh = sigm(acc[mt][1][r]) * tanh_f(cn);
            h0sv[mt][r] = hh;
            hv[mt][r] = hh;
          }
        #pragma unroll
        for (int mt = 0; mt < 2; ++mt)
          #pragma unroll
          for (int r = 0; r < 4; ++r) {
            const float other = __shfl_xor(hv[mt][r], 1);
            if (!(u & 1))
              store_h_pair(h0wr, w, u, mi * 32 + mt * 16 + q * 4 + r, hv[mt][r], other);
          }
      }
    }
    group_barrier(ctr, &phase, zz);

    // ======== Layer 1: gates = [h0_new | h1_prev] @ W^T ========
    {
      const _Float16* h0nw = hbL(0, t & 1);
      const _Float16* h1rd = hbL(1, (t + 1) & 1);
      f32x4 acc[2][2];
      #pragma unroll
      for (int mt = 0; mt < 2; ++mt)
        #pragma unroll
        for (int nt = 0; nt < 2; ++nt) {
          f32x4 v; v[0] = biasL1[nt]; v[1] = biasL1[nt]; v[2] = biasL1[nt]; v[3] = biasL1[nt];
          acc[mt][nt] = v;
        }
      #pragma unroll
      for (int kt = 0; kt < 16; ++kt) {
        half8 a[2];
        #pragma unroll
        for (int mt = 0; mt < 2; ++mt) {
          const int m = mi * 32 + mt * 16 + u;
          if (kt < 8) a[mt] = ld_frag(h0nw, (kt * 4 + q) * 64 + m);
          else        a[mt] = ld_frag(h1rd, ((kt - 8) * 4 + q) * 64 + m);
        }
        #pragma unroll
        for (int mt = 0; mt < 2; ++mt)
          #pragma unroll
          for (int nt = 0; nt < 2; ++nt)
            acc[mt][nt] = __builtin_amdgcn_mfma_f32_16x16x32_f16(a[mt], bL1[nt][kt], acc[mt][nt], 0, 0, 0);
      }
      if (ni == 0) {
        #pragma unroll
        for (int mt = 0; mt < 2; ++mt)
          #pragma unroll
          for (int r = 0; r < 4; ++r)
            exch[(mi * 8 + mt * 4 + r) * 64 + lane] = sigm(acc[mt][0][r]) * tanh_f(acc[mt][1][r]);
      }
      __syncthreads();
      if (ni == 1) {
        _Float16* h1wr = hbL(1, t & 1);
        float hv[2][4];
        #pragma unroll
        for (int mt = 0; mt < 2; ++mt)
          #pragma unroll
          for (int r = 0; r < 4; ++r) {
            const float u0 = exch[(mi * 8 + mt * 4 + r) * 64 + lane];
            const float cn = sigm(acc[mt][0][r]) * c1st[mt][r] + u0;
            c1st[mt][r] = cn;
            const float hh = sigm(acc[mt][1][r]) * tanh_f(cn);
            h1sv[mt][r] = hh;
            hv[mt][r] = hh;
          }
        #pragma unroll
        for (int mt = 0; mt < 2; ++mt)
          #pragma unroll
          for (int r = 0; r < 4; ++r) {
            const float other = __shfl_xor(hv[mt][r], 1);
            if (!(u & 1))
              store_h_pair(h1wr, w, u, mi * 32 + mt * 16 + q * 4 + r, hv[mt][r], other);
          }
      }
    }
    group_barrier(ctr, &phase, zz);

    // ======== FC + log_softmax (computed redundantly per WG) ========
    {
      const _Float16* h1nw = hbL(1, t & 1);
      f32x4 acc[2][2];
      #pragma unroll
      for (int mt = 0; mt < 2; ++mt)
        #pragma unroll
        for (int nt = 0; nt < 2; ++nt) {
          f32x4 v; v[0] = biasFC[nt]; v[1] = biasFC[nt]; v[2] = biasFC[nt]; v[3] = biasFC[nt];
          acc[mt][nt] = v;
        }
      #pragma unroll
      for (int kt = 0; kt < 8; ++kt) {
        half8 a[2];
        #pragma unroll
        for (int mt = 0; mt < 2; ++mt) {
          const int m = mi * 32 + mt * 16 + u;
          a[mt] = ld_frag(h1nw, (kt * 4 + q) * 64 + m);
        }
        #pragma unroll
        for (int mt = 0; mt < 2; ++mt)
          #pragma unroll
          for (int nt = 0; nt < 2; ++nt)
            acc[mt][nt] = __builtin_amdgcn_mfma_f32_16x16x32_f16(a[mt], bFC[nt][kt], acc[mt][nt], 0, 0, 0);
      }
      #pragma unroll
      for (int mt = 0; mt < 2; ++mt)
        #pragma unroll
        for (int nt = 0; nt < 2; ++nt)
          #pragma unroll
          for (int r = 0; r < 4; ++r)
            predbuf[(mi * 32 + mt * 16 + q * 4 + r) * 68 + ni * 32 + nt * 16 + u] = acc[mt][nt][r];
    }
    __syncthreads();
    {
      const int row = tid >> 2;   // group-local chain
      const int cg  = tid & 3;    // 16-col group
      const float* pr = predbuf + row * 68 + cg * 16;
      float p[16];
      #pragma unroll
      for (int j = 0; j < 16; ++j) p[j] = pr[j];
      float mx = -3.0e38f;
      #pragma unroll
      for (int j = 0; j < 16; ++j)
        if (!(cg == 3 && j == 15)) mx = fmaxf(mx, p[j]);   // exclude col 63 (dur)
      mx = fmaxf(mx, __shfl_xor(mx, 1));
      mx = fmaxf(mx, __shfl_xor(mx, 2));
      float sm = 0.0f;
      #pragma unroll
      for (int j = 0; j < 16; ++j)
        if (!(cg == 3 && j == 15)) sm += __expf(p[j] - mx);
      sm += __shfl_xor(sm, 1);
      sm += __shfl_xor(sm, 2);
      const float lz = mx + __logf(sm);
      float o[16];
      #pragma unroll
      for (int j = 0; j < 16; ++j) o[j] = p[j] - lz;
      if (cg == 3) o[15] = sigm(p[15]);                    // duration = sigmoid(pred[63])
      _Float16* xw = xbuf + row * 72 + cg * 16;            // feedback x = out (f16)
      #pragma unroll
      for (int j = 0; j < 16; ++j) xw[j] = (_Float16)o[j];
      if ((row >> 2) == w) {                               // each WG writes 4 of the 64 rows
        const int ch = g * 64 + row;
        float* dst = out + ((size_t)ch * TSTEPS + t) * 64 + cg * 16;
        #pragma unroll
        for (int j = 0; j < 16; ++j) dst[j] = o[j];
      }
    }
    __syncthreads();
  }

  // ---------------- final h_f, c_f ----------------
  if (ni == 1) {
    float* hf = out + OUT_ELEMS;
    float* cf = out + OUT_ELEMS + HF_ELEMS;
    #pragma unroll
    for (int mt = 0; mt < 2; ++mt)
      #pragma unroll
      for (int r = 0; r < 4; ++r) {
        const int ch = g * 64 + mi * 32 + mt * 16 + q * 4 + r;
        const size_t idx = (size_t)ch * 256 + w * 16 + u;
        hf[idx] = h0sv[mt][r];
        hf[262144 + idx] = h1sv[mt][r];
        cf[idx] = c0st[mt][r];
        cf[262144 + idx] = c1st[mt][r];
      }
  }
}

extern "C" void kernel_launch(void* const* d_in, const int* in_sizes, int n_in,
                              void* d_out, int out_size, void* d_ws, size_t ws_size,
                              hipStream_t stream) {
  (void)in_sizes; (void)n_in; (void)out_size;
  if (ws_size < (size_t)WS_NEEDED) return;

  const float* h0   = (const float*)d_in[1];
  const float* c0   = (const float*)d_in[2];
  const float* Wih0 = (const float*)d_in[3];
  const float* Whh0 = (const float*)d_in[4];
  const float* bih0 = (const float*)d_in[5];
  const float* bhh0 = (const float*)d_in[6];
  const float* Wih1 = (const float*)d_in[7];
  const float* Whh1 = (const float*)d_in[8];
  const float* bih1 = (const float*)d_in[9];
  const float* bhh1 = (const float*)d_in[10];
  const float* Wfc  = (const float*)d_in[11];
  const float* bfc  = (const float*)d_in[12];
  float* outp = (float*)d_out;
  char*  wsp  = (char*)d_ws;

  // zero barrier + slot counters (ws is re-poisoned to 0xAA before every
  // launch; end-of-dispatch flush of the memset makes zeros globally visible)
  hipMemsetAsync(d_ws, 0, WS_HBUF_OFF, stream);

  void* args[] = { &h0, &c0, &Wih0, &Whh0, &bih0, &bhh0, &Wih1, &Whh1,
                   &bih1, &bhh1, &Wfc, &bfc, &outp, &wsp };
  hipError_t e = hipLaunchCooperativeKernel((const void*)decoder_kernel,
                                            dim3(NGROUP * GWG), dim3(NTHR),
                                            args, 0u, stream);
  if (e != hipSuccess) {
    // fallback: plain launch (256 full-CU blocks on 256 CUs are co-resident)
    decoder_kernel<<<dim3(NGROUP * GWG), dim3(NTHR), 0, stream>>>(
        h0, c0, Wih0, Whh0, bih0, bhh0, Wih1, Whh1, bih1, bhh1, Wfc, bfc, outp, wsp);
  }
}